// Round 14
// baseline (431.759 us; speedup 1.0000x reference)
//
#include <hip/hip_runtime.h>

#define D_ 1024
#define S_ 2048
#define B_ 32
#define BM 256
#define BN 256
#define BK 64
#define NKT 32   // K tiles: 16 from W/k + 16 from U/q (BK=64)

typedef __attribute__((ext_vector_type(8))) _Float16 f16x8;  // 4 VGPR MFMA operand
typedef __attribute__((ext_vector_type(16))) float f32x16;   // MFMA 32x32 acc

// async global->LDS, 16B per lane; LDS dest = wave-uniform base + lane*16.
__device__ __forceinline__ void async_ld16(const void* g, void* l) {
  __builtin_amdgcn_global_load_lds(
      (const __attribute__((address_space(1))) void*)g,
      (__attribute__((address_space(3))) void*)l, 16, 0, 0);
}

// ---------------------------------------------------------------------------
// prep: W,U -> f16, FRAGMENT ORDER per 256x64 A-tile (2048 granules of 8):
//   granule = ((ks*8 + wr*4 + fm) << 6) | lane   (verified R9-R13)
// ---------------------------------------------------------------------------
__global__ void prep_kernel(const float* __restrict__ W, const float* __restrict__ U,
                            _Float16* __restrict__ wf, _Float16* __restrict__ uf) {
  int t = blockIdx.x * blockDim.x + threadIdx.x;  // [0, 131072) granules
  const float* src = blockIdx.y ? U : W;
  _Float16* dst = blockIdx.y ? uf : wf;

  int tile = t >> 11;        // [0,64) = dblk*16 + ktt
  int g    = t & 2047;
  int top  = g >> 6;         // [0,32) = ks*8 + wr*4 + fm
  int ks = top >> 3, wr = (top >> 2) & 1, fm = top & 3;
  int lane = g & 63, l31 = lane & 31, lhi = lane >> 5;
  int row   = wr * 128 + fm * 32 + l31;
  int chunk = ks * 2 + lhi;
  int d = (tile >> 4) * 256 + row;
  int e = (tile & 15) * 64 + chunk * 8;

  const float* p = src + (size_t)d * D_ + e;
  f16x8 hv;
#pragma unroll
  for (int j = 0; j < 8; ++j) hv[j] = (_Float16)p[j];  // RN
  *(f16x8*)(dst + (size_t)t * 8) = hv;                 // linear, coalesced
}

// ---------------------------------------------------------------------------
// kqprep: k,q (f32 [b,e,s]) -> f16 fragment-order B-tiles in ws (R11 verified).
// ---------------------------------------------------------------------------
__global__ void kqprep_kernel(const float* __restrict__ kten, const float* __restrict__ qten,
                              _Float16* __restrict__ bfmt) {
  size_t t = (size_t)blockIdx.x * 256 + threadIdx.x;  // [0, 16777216)
  int g    = (int)(t & 2047);
  int tile = (int)(t >> 11);
  int st   = tile & 7;
  int ktt  = (tile >> 3) & 15;
  int half = (tile >> 7) & 1;
  int b    = tile >> 8;
  int l31 = g & 31, clh = (g >> 5) & 1, w2 = (g >> 6) & 7, cks = g >> 9;
  int n = w2 * 32 + l31;
  int c = cks * 2 + clh;
  int e = ktt * 64 + c * 8;
  int s = st * 256 + n;

  const float* src = (half ? qten : kten) + (size_t)b * (D_ * S_) + (size_t)e * S_ + s;
  f16x8 hv;
#pragma unroll
  for (int j = 0; j < 8; ++j) hv[j] = (_Float16)src[(size_t)j * S_];  // RN
  *(f16x8*)(bfmt + t * 8) = hv;
}

// ---------------------------------------------------------------------------
// gemm v14: R13 geometry + REGISTER FRAGMENT DOUBLE-BUFFERING so the LDS pipe
// overlaps the MFMA pipe (R13 serialized them: phase = reads THEN MFMAs).
// 128 K=16 sub-phases; sub-phase s:
//   2 gll issue | 6 ds_read (frags for s+1, from LDS buf[(s+1)>>1 &3]) |
//   sched_barrier | setprio 8 MFMA (frags loaded at s-1) setprio |
//   [vmcnt(6) on even s] | s_barrier | sched_barrier(0)
// vmcnt ledger (2 gll/sub-phase, buffers issued 3 half-K ahead): steady
// even-end vmcnt(6) retires exactly the buffer needed 1 sub-phase later;
// never drains to 0 mid-loop. Tail drains 6 -> 4 -> 0.
// Frag sets: 2 x (4A+2B) x 4 VGPR = 48 (same as R13's single 12-frag set).
// ---------------------------------------------------------------------------
__global__ void __launch_bounds__(512, 2)
gemm_kernel(const float* __restrict__ v,
            const _Float16* __restrict__ wf, const _Float16* __restrict__ uf,
            const _Float16* __restrict__ bfmt,
            float* __restrict__ partials) {
  __shared__ __align__(16) _Float16 Af[4][BM * 32];  // 4 x 16 KB half-K bufs
  __shared__ __align__(16) _Float16 Bf[4][BN * 32];  // 4 x 16 KB
  __shared__ float vbuf[BM];
  __shared__ float red[2][BN];

  const int tid  = threadIdx.x;
  const int lane = tid & 63;
  const int wid  = tid >> 6;
  const int wr   = wid >> 2;        // [0,2) d-half (128 rows)
  const int wc   = wid & 3;         // [0,4) s-quarter (64 cols)

  int bid  = blockIdx.x;
  int g    = ((bid >> 5) << 3) | (bid & 7);  // [0,256): 4 dblk siblings same XCD
  int dblk = (bid >> 3) & 3;
  int st   = g & 7;
  int b    = g >> 3;
  int s0   = st * BN;

  if (tid < BM) vbuf[tid] = v[(size_t)b * D_ + dblk * BM + tid];
  __syncthreads();  // drain divergent v-load: vmcnt ledger starts at 0

  f32x16 acc[4][2];
#pragma unroll
  for (int i = 0; i < 4; ++i)
#pragma unroll
    for (int j = 0; j < 2; ++j)
#pragma unroll
      for (int r = 0; r < 16; ++r) acc[i][j][r] = 0.0f;

#define PH_FENCE asm volatile("" ::: "memory")
#define WAIT8 asm volatile("s_waitcnt vmcnt(8)" ::: "memory")
#define WAIT6 asm volatile("s_waitcnt vmcnt(6)" ::: "memory")
#define WAIT4 asm volatile("s_waitcnt vmcnt(4)" ::: "memory")
#define WAIT0 asm volatile("s_waitcnt vmcnt(0)" ::: "memory")

// Issue HALF of half-K subtile h_ (1 A gll + 1 B gll = 2 vmem instr).
#define GLLH2(h_, part_) do {                                                  \
    const int kt_ = (h_) >> 1, hh_ = (h_) & 1, bi_ = (h_) & 3;                 \
    const int half_ = kt_ >> 4, ktt_ = kt_ & 15;                               \
    const _Float16* at_ = (half_ ? uf : wf)                                    \
        + (size_t)(dblk * 16 + ktt_) * 16384 + (size_t)hh_ * 8192;             \
    const _Float16* bt_ = bfmt                                                 \
        + ((size_t)(((b * 2 + half_) * 16 + ktt_) * 8 + st)) * 16384           \
        + (size_t)hh_ * 8192;                                                  \
    async_ld16(at_ + (size_t)(tid + (part_) * 512) * 8,                        \
               &Af[bi_][(size_t)(tid + (part_) * 512) * 8]);                   \
    async_ld16(bt_ + (size_t)(tid + (part_) * 512) * 8,                        \
               &Bf[bi_][(size_t)(tid + (part_) * 512) * 8]);                   \
  } while (0)

// 6 ds_read_b128: one K=16 slice of fragments (zero conflicts, verified).
#define DSREAD6(A_, B_, bi_, sl_) do {                                         \
    _Pragma("unroll")                                                          \
    for (int fm = 0; fm < 4; ++fm)                                             \
      A_[fm] = *(const f16x8*)&Af[bi_][(size_t)((((sl_) * 8 + wr * 4 + fm) * 64 + lane)) * 8]; \
    _Pragma("unroll")                                                          \
    for (int fn = 0; fn < 2; ++fn)                                             \
      B_[fn] = *(const f16x8*)&Bf[bi_][(size_t)((((sl_) * 8 + wc * 2 + fn) * 64 + lane)) * 8]; \
  } while (0)

#define MFMA8(A_, B_) do {                                                     \
    __builtin_amdgcn_s_setprio(1);                                             \
    _Pragma("unroll")                                                          \
    for (int fm = 0; fm < 4; ++fm)                                             \
      _Pragma("unroll")                                                        \
      for (int fn = 0; fn < 2; ++fn)                                           \
        acc[fm][fn] = __builtin_amdgcn_mfma_f32_32x32x16_f16(A_[fm], B_[fn], acc[fm][fn], 0, 0, 0); \
    __builtin_amdgcn_s_setprio(0);                                             \
  } while (0)

// Sub-phase: issue | read next frags | MFMA current frags | wait | barrier.
#define SUB(rdbi_, rdsl_, CA, CB, NA, NB, ISSUE, WAITC) do {                   \
    PH_FENCE;                                                                  \
    ISSUE;                                                                     \
    DSREAD6(NA, NB, rdbi_, rdsl_);                                             \
    __builtin_amdgcn_sched_barrier(0);                                         \
    MFMA8(CA, CB);                                                             \
    WAITC;                                                                     \
    __builtin_amdgcn_s_barrier();                                              \
    __builtin_amdgcn_sched_barrier(0);                                         \
  } while (0)

  f16x8 fa0[4], fb0[2], fa1[4], fb1[2];

  // --- prologue: issue buffers 0,1,2 (12 vmem); buffer 0 ready; load set0 ---
  PH_FENCE;
  GLLH2(0, 0); GLLH2(0, 1);
  GLLH2(1, 0); GLLH2(1, 1);
  GLLH2(2, 0); GLLH2(2, 1);
  WAIT8;                       // buffer 0 complete (8 left: bufs 1,2)
  __builtin_amdgcn_s_barrier();
  __builtin_amdgcn_sched_barrier(0);
  DSREAD6(fa0, fb0, 0, 0);     // frags for sub-phase 0

  // --- main loop: macro-iter m covers s = 8m..8m+7 (m = 0..14, s <= 119) ----
  for (int m = 0; m < 15; ++m) {
    const int h3 = 4 * m + 3, h4 = 4 * m + 4, h5 = 4 * m + 5, h6 = 4 * m + 6;
    SUB(0, 1, fa0, fb0, fa1, fb1, GLLH2(h3, 0), WAIT6);  // s=8m+0
    SUB(1, 0, fa1, fb1, fa0, fb0, GLLH2(h3, 1),      );  // s=8m+1
    SUB(1, 1, fa0, fb0, fa1, fb1, GLLH2(h4, 0), WAIT6);  // s=8m+2
    SUB(2, 0, fa1, fb1, fa0, fb0, GLLH2(h4, 1),      );  // s=8m+3
    SUB(2, 1, fa0, fb0, fa1, fb1, GLLH2(h5, 0), WAIT6);  // s=8m+4
    SUB(3, 0, fa1, fb1, fa0, fb0, GLLH2(h5, 1),      );  // s=8m+5
    SUB(3, 1, fa0, fb0, fa1, fb1, GLLH2(h6, 0), WAIT6);  // s=8m+6
    SUB(0, 0, fa1, fb1, fa0, fb0, GLLH2(h6, 1),      );  // s=8m+7
  }
  // --- tail: s = 120..127 (issues only for h=63; ledger 6 -> 4 -> 0) --------
  SUB(0, 1, fa0, fb0, fa1, fb1, GLLH2(63, 0), WAIT6);    // s=120
  SUB(1, 0, fa1, fb1, fa0, fb0, GLLH2(63, 1),      );    // s=121
  SUB(1, 1, fa0, fb0, fa1, fb1,             , WAIT4);    // s=122
  SUB(2, 0, fa1, fb1, fa0, fb0,             ,      );    // s=123
  SUB(2, 1, fa0, fb0, fa1, fb1,             , WAIT0);    // s=124
  SUB(3, 0, fa1, fb1, fa0, fb0,             ,      );    // s=125
  SUB(3, 1, fa0, fb0, fa1, fb1,             ,      );    // s=126
  PH_FENCE;
  MFMA8(fa1, fb1);                                       // s=127

#undef SUB
#undef MFMA8
#undef DSREAD6
#undef GLLH2
#undef WAIT0
#undef WAIT4
#undef WAIT6
#undef WAIT8
#undef PH_FENCE

  // ---- epilogue: tanh, weight by v[d], column-reduce the 256 d-rows ----
  float psum[2] = {0.f, 0.f};
#pragma unroll
  for (int fm = 0; fm < 4; ++fm)
#pragma unroll
    for (int fn = 0; fn < 2; ++fn)
#pragma unroll
      for (int r = 0; r < 16; ++r) {
        // C/D layout: col = lane&31, row = (r&3)+8*(r>>2)+4*(lane>>5)
        int row = wr * 128 + fm * 32 + (r & 3) + 8 * (r >> 2) + 4 * (lane >> 5);
        float x  = acc[fm][fn][r];
        float th = 1.0f - 2.0f / (__expf(2.0f * x) + 1.0f);  // tanh(x)
        psum[fn] += vbuf[row] * th;
      }
#pragma unroll
  for (int fn = 0; fn < 2; ++fn) psum[fn] += __shfl_xor(psum[fn], 32);
  if (lane < 32) {
    red[wr][wc * 64 + lane]      = psum[0];
    red[wr][wc * 64 + 32 + lane] = psum[1];
  }
  __syncthreads();
  if (tid < BN) {
    float val = red[0][tid] + red[1][tid];
    partials[(size_t)(dblk * B_ + b) * S_ + s0 + tid] = val;
  }
}

// ---------------------------------------------------------------------------
// gemm fallback = R10 verbatim (reg-staged B, counted vmcnt(32)); used when
// ws_size can't hold the 256MB prepped-B buffer.
// ---------------------------------------------------------------------------
__global__ void __launch_bounds__(512, 2)
gemm_fb_kernel(const float* __restrict__ kten, const float* __restrict__ qten,
               const float* __restrict__ v,
               const _Float16* __restrict__ wf, const _Float16* __restrict__ uf,
               float* __restrict__ partials) {
  __shared__ __align__(16) _Float16 Af[2][BM * BK];
  __shared__ __align__(16) _Float16 Bf[2][BN * BK];
  __shared__ float vbuf[BM];
  __shared__ float red[2][BN];

  const int tid  = threadIdx.x;
  const int lane = tid & 63;
  const int wid  = tid >> 6;
  const int wr   = wid >> 2;
  const int wc   = wid & 3;

  int bid  = blockIdx.x;
  int g    = ((bid >> 5) << 3) | (bid & 7);
  int dblk = (bid >> 3) & 3;
  int st   = g & 7;
  int b    = g >> 3;
  int s0   = st * BN;

  if (tid < BM) vbuf[tid] = v[(size_t)b * D_ + dblk * BM + tid];

  f32x16 acc[4][2];
#pragma unroll
  for (int i = 0; i < 4; ++i)
#pragma unroll
    for (int j = 0; j < 2; ++j)
#pragma unroll
      for (int r = 0; r < 16; ++r) acc[i][j][r] = 0.0f;

  const int nB = tid & 255;
  const int kq = tid >> 8;

#define PH_FENCE_F asm volatile("" ::: "memory")
#define PH_BAR_F __builtin_amdgcn_s_barrier()

#define GLLA_F(ktn, buf, part) do {                                            \
    const int half_ = (ktn) >> 4, ktt_ = (ktn) & 15;                           \
    const _Float16* at_ = (half_ ? uf : wf) + (size_t)(dblk * 16 + ktt_) * 16384; \
    async_ld16(at_ + (size_t)(tid + (part) * 1024) * 8,                        \
               &Af[buf][(size_t)(tid + (part) * 1024) * 8]);                   \
    async_ld16(at_ + (size_t)(tid + (part) * 1024 + 512) * 8,                  \
               &Af[buf][(size_t)(tid + (part) * 1024 + 512) * 8]);             \
  } while (0)

#define LOADB_F(ktn, xv, h) do {                                               \
    const int half_ = (ktn) >> 4, ktt_ = (ktn) & 15;                           \
    const float* col_ = (half_ ? qten : kten) + (size_t)b * (D_ * S_)          \
                        + (size_t)(ktt_ * 64) * S_ + s0 + nB                   \
                        + (size_t)(kq * 32) * S_;                              \
    _Pragma("unroll")                                                          \
    for (int j = 16 * (h); j < 16 * (h) + 16; ++j) xv[j] = col_[(size_t)j * S_]; \
  } while (0)

#define CVTWRITE_F(xv, buf) do {                                               \
    _Pragma("unroll")                                                          \
    for (int cl = 0; cl < 4; ++cl) {                                           \
      f16x8 hv_;                                                               \
      _Pragma("unroll")                                                        \
      for (int w = 0; w < 8; ++w) hv_[w] = (_Float16)xv[cl * 8 + w];           \
      int c_ = kq * 4 + cl, cks_ = c_ >> 1, clh_ = c_ & 1;                     \
      int gnl_ = ((cks_ * 8 + (nB >> 6) * 2 + ((nB >> 5) & 1)) << 6)           \
                 | (clh_ << 5) | (nB & 31);                                    \
      *(f16x8*)&Bf[buf][(size_t)gnl_ * 8] = hv_;                               \
    }                                                                          \
  } while (0)

#define COMPUTE_PHASE_F(cur_, ks_) do {                                        \
    f16x8 af_[4], bf_[2];                                                      \
    _Pragma("unroll")                                                          \
    for (int fm = 0; fm < 4; ++fm)                                             \
      af_[fm] = *(const f16x8*)&Af[cur_][(size_t)(((ks_) * 8 + wr * 4 + fm) * 64 + lane) * 8]; \
    _Pragma("unroll")                                                          \
    for (int fn = 0; fn < 2; ++fn)                                             \
      bf_[fn] = *(const f16x8*)&Bf[cur_][(size_t)(((ks_) * 8 + wc * 2 + fn) * 64 + lane) * 8]; \
    __builtin_amdgcn_s_setprio(1);                                             \
    _Pragma("unroll")                                                          \
    for (int fm = 0; fm < 4; ++fm)                                             \
      _Pragma("unroll")                                                        \
      for (int fn = 0; fn < 2; ++fn)                                           \
        acc[fm][fn] = __builtin_amdgcn_mfma_f32_32x32x16_f16(af_[fm], bf_[fn], acc[fm][fn], 0, 0, 0); \
    __builtin_amdgcn_s_setprio(0);                                             \
  } while (0)

#define STEP_F(kt_, cur_, xvC_, xvN_) do {                                     \
    const int nxt_ = (cur_) ^ 1;                                               \
    PH_FENCE_F; GLLA_F((kt_) + 1, nxt_, 0); COMPUTE_PHASE_F(cur_, 0); PH_BAR_F;\
    PH_FENCE_F; GLLA_F((kt_) + 1, nxt_, 1); COMPUTE_PHASE_F(cur_, 1); PH_BAR_F;\
    PH_FENCE_F; LOADB_F((kt_) + 2, xvN_, 0); COMPUTE_PHASE_F(cur_, 2); PH_BAR_F;\
    PH_FENCE_F; LOADB_F((kt_) + 2, xvN_, 1); CVTWRITE_F(xvC_, nxt_);           \
              COMPUTE_PHASE_F(cur_, 3);                                        \
    asm volatile("s_waitcnt vmcnt(32) lgkmcnt(0)" ::: "memory");               \
    PH_BAR_F;                                                                  \
    __builtin_amdgcn_sched_barrier(0);                                         \
  } while (0)

  float xvA[32], xvB[32];
  LOADB_F(0, xvA, 0); LOADB_F(0, xvA, 1);
  GLLA_F(0, 0, 0);    GLLA_F(0, 0, 1);
  LOADB_F(1, xvB, 0); LOADB_F(1, xvB, 1);
  CVTWRITE_F(xvA, 0);
  __syncthreads();

  for (int it = 0; it < 15; ++it) {
    STEP_F(2 * it,     0, xvB, xvA);
    STEP_F(2 * it + 1, 1, xvA, xvB);
  }

  PH_FENCE_F; GLLA_F(31, 1, 0); COMPUTE_PHASE_F(0, 0); PH_BAR_F;
  PH_FENCE_F; GLLA_F(31, 1, 1); COMPUTE_PHASE_F(0, 1); PH_BAR_F;
  PH_FENCE_F; COMPUTE_PHASE_F(0, 2); PH_BAR_F;
  PH_FENCE_F; CVTWRITE_F(xvB, 1); COMPUTE_PHASE_F(0, 3);
  __syncthreads();
  COMPUTE_PHASE_F(1, 0); COMPUTE_PHASE_F(1, 1); COMPUTE_PHASE_F(1, 2); COMPUTE_PHASE_F(1, 3);

#undef STEP_F
#undef COMPUTE_PHASE_F
#undef CVTWRITE_F
#undef LOADB_F
#undef GLLA_F
#undef PH_BAR_F
#undef PH_FENCE_F

  float psum[2] = {0.f, 0.f};
#pragma unroll
  for (int fm = 0; fm < 4; ++fm)
#pragma unroll
    for (int fn = 0; fn < 2; ++fn)
#pragma unroll
      for (int r = 0; r < 16; ++r) {
        int row = wr * 128 + fm * 32 + (r & 3) + 8 * (r >> 2) + 4 * (lane >> 5);
        float x  = acc[fm][fn][r];
        float th = 1.0f - 2.0f / (__expf(2.0f * x) + 1.0f);
        psum[fn] += vbuf[row] * th;
      }
#pragma unroll
  for (int fn = 0; fn < 2; ++fn) psum[fn] += __shfl_xor(psum[fn], 32);
  if (lane < 32) {
    red[wr][wc * 64 + lane]      = psum[0];
    red[wr][wc * 64 + 32 + lane] = psum[1];
  }
  __syncthreads();
  if (tid < BN) {
    float val = red[0][tid] + red[1][tid];
    partials[(size_t)(dblk * B_ + b) * S_ + s0 + tid] = val;
  }
}

// ---------------------------------------------------------------------------
// softmax over S per batch; sums the 4 d-block partials first. Deterministic.
// ---------------------------------------------------------------------------
__global__ void softmax_kernel(const float* __restrict__ partials, float* __restrict__ out) {
  __shared__ float logit[S_];
  __shared__ float wred[2][4];
  int b = blockIdx.x, tid = threadIdx.x;
  int lane = tid & 63, wid = tid >> 6;
  float lmax = -1e30f;
  for (int i = tid; i < S_; i += 256) {
    float acc = 0.f;
#pragma unroll
    for (int d = 0; d < 4; ++d) acc += partials[(size_t)(d * B_ + b) * S_ + i];
    logit[i] = acc;
    lmax = fmaxf(lmax, acc);
  }
#pragma unroll
  for (int o = 32; o; o >>= 1) lmax = fmaxf(lmax, __shfl_xor(lmax, o));
  if (lane == 0) wred[0][wid] = lmax;
  __syncthreads();
  float m = fmaxf(fmaxf(wred[0][0], wred[0][1]), fmaxf(wred[0][2], wred[0][3]));
  float lsum = 0.f;
  for (int i = tid; i < S_; i += 256) {
    float ex = __expf(logit[i] - m);
    logit[i] = ex;
    lsum += ex;
  }
#pragma unroll
  for (int o = 32; o; o >>= 1) lsum += __shfl_xor(lsum, o);
  if (lane == 0) wred[1][wid] = lsum;
  __syncthreads();
  float tot = wred[1][0] + wred[1][1] + wred[1][2] + wred[1][3];
  float inv = 1.0f / tot;
  for (int i = tid; i < S_; i += 256) out[(size_t)b * S_ + i] = logit[i] * inv;
}

extern "C" void kernel_launch(void* const* d_in, const int* in_sizes, int n_in,
                              void* d_out, int out_size, void* d_ws, size_t ws_size,
                              hipStream_t stream) {
  const float* q = (const float*)d_in[0];
  const float* k = (const float*)d_in[1];
  const float* v = (const float*)d_in[2];
  const float* W = (const float*)d_in[3];
  const float* U = (const float*)d_in[4];

  // ws: [wf 2MB][uf 2MB][partials 1MB][bfmt 256MB (optional)]
  _Float16* wf = (_Float16*)d_ws;
  _Float16* uf = wf + (size_t)D_ * D_;
  float* partials = (float*)(uf + (size_t)D_ * D_);
  _Float16* bfmt = (_Float16*)((char*)d_ws + 5242880);
  const size_t NEED = 5242880ull + 268435456ull;  // 262 MB

  prep_kernel<<<dim3(512, 2), 256, 0, stream>>>(W, U, wf, uf);
  if (ws_size >= NEED) {
    kqprep_kernel<<<dim3(65536), 256, 0, stream>>>(k, q, bfmt);
    gemm_kernel<<<dim3(1024), 512, 0, stream>>>(v, wf, uf, bfmt, partials);
  } else {
    gemm_fb_kernel<<<dim3(1024), 512, 0, stream>>>(k, q, v, wf, uf, partials);
  }
  softmax_kernel<<<dim3(B_), 256, 0, stream>>>(partials, (float*)d_out);
}

// Round 15
// 426.878 us; speedup vs baseline: 1.0114x; 1.0114x over previous
//
#include <hip/hip_runtime.h>

#define D_ 1024
#define S_ 2048
#define B_ 32
#define BM 256
#define BN 128
#define NKT 32   // K tiles of 64: 16 from W/k + 16 from U/q
#define NPH 64   // half-K (K=32) phases

typedef __attribute__((ext_vector_type(8))) _Float16 f16x8;  // 4 VGPR MFMA operand
typedef __attribute__((ext_vector_type(16))) float f32x16;   // MFMA 32x32 acc

// async global->LDS, 16B per lane; LDS dest = wave-uniform base + lane*16.
__device__ __forceinline__ void async_ld16(const void* g, void* l) {
  __builtin_amdgcn_global_load_lds(
      (const __attribute__((address_space(1))) void*)g,
      (__attribute__((address_space(3))) void*)l, 16, 0, 0);
}

// ---------------------------------------------------------------------------
// prep: W,U -> f16, FRAGMENT ORDER per 256x64 A-tile (2048 granules of 8):
//   granule = ((ks*8 + wr*4 + fm) << 6) | lane   (verified R9-R14)
// ---------------------------------------------------------------------------
__global__ void prep_kernel(const float* __restrict__ W, const float* __restrict__ U,
                            _Float16* __restrict__ wf, _Float16* __restrict__ uf) {
  int t = blockIdx.x * blockDim.x + threadIdx.x;  // [0, 131072) granules
  const float* src = blockIdx.y ? U : W;
  _Float16* dst = blockIdx.y ? uf : wf;

  int tile = t >> 11;        // [0,64) = dblk*16 + ktt
  int g    = t & 2047;
  int top  = g >> 6;         // [0,32) = ks*8 + wr*4 + fm
  int ks = top >> 3, wr = (top >> 2) & 1, fm = top & 3;
  int lane = g & 63, l31 = lane & 31, lhi = lane >> 5;
  int row   = wr * 128 + fm * 32 + l31;
  int chunk = ks * 2 + lhi;
  int d = (tile >> 4) * 256 + row;
  int e = (tile & 15) * 64 + chunk * 8;

  const float* p = src + (size_t)d * D_ + e;
  f16x8 hv;
#pragma unroll
  for (int j = 0; j < 8; ++j) hv[j] = (_Float16)p[j];  // RN
  *(f16x8*)(dst + (size_t)t * 8) = hv;                 // linear, coalesced
}

// ---------------------------------------------------------------------------
// kqprep: k,q (f32 [b,e,s]) -> f16 fragment-order B-tiles, BN=128 tiling.
// Tile (b, half, ktt, st16) = 128 s x 64 k = 16KB, 1024 granules:
//   g: l31=g&31, clh=(g>>5)&1, w2=(g>>6)&3, cks=(g>>8)&3
//   n = w2*32+l31 (s in tile), c = cks*2+clh, e = ktt*64+c*8, s = st16*128+n
// cks-major => half-K (cks<2) is the first contiguous 512 granules.
// Same per-element mapping as R11-R14 (verified), retiled to 128-s tiles.
// ---------------------------------------------------------------------------
__global__ void kqprep_kernel(const float* __restrict__ kten, const float* __restrict__ qten,
                              _Float16* __restrict__ bfmt) {
  size_t t = (size_t)blockIdx.x * 256 + threadIdx.x;  // [0, 16777216)
  int g    = (int)(t & 1023);
  int tile = (int)(t >> 10);        // [0,16384) = ((b*2+half)*16 + ktt)*16 + st
  int st   = tile & 15;
  int ktt  = (tile >> 4) & 15;
  int half = (tile >> 8) & 1;
  int b    = tile >> 9;
  int l31 = g & 31, clh = (g >> 5) & 1, w2 = (g >> 6) & 3, cks = (g >> 8) & 3;
  int n = w2 * 32 + l31;
  int c = cks * 2 + clh;
  int e = ktt * 64 + c * 8;
  int s = st * 128 + n;

  const float* src = (half ? qten : kten) + (size_t)b * (D_ * S_) + (size_t)e * S_ + s;
  f16x8 hv;
#pragma unroll
  for (int j = 0; j < 8; ++j) hv[j] = (_Float16)src[(size_t)j * S_];  // RN
  *(f16x8*)(bfmt + t * 8) = hv;
}

// ---------------------------------------------------------------------------
// gemm v15: SAME deep counted-vmcnt schedule as R13 (best: 318us, MfmaUtil 41%)
// but split into 4-wave / 256x128 blocks with 75.8KB LDS -> TWO independent
// barrier groups per CU. R13's counters fit LDS+MFMA+VALU summed SERIALLY:
// one 8-wave barrier group makes the whole CU alternate read-burst/MFMA-burst.
// Two groups interleave bursts -> pipes overlap (m114 mechanism).
// Phase h: 12 ds_read buf[h%3] | 6 gll half(h+2)->buf[(h+2)%3] | s_barrier |
// lgkmcnt(0)+sched_barrier | setprio 16 MFMA setprio | vmcnt(6) | s_barrier.
// Ledger (6 gll/phase): steady 12 in flight; WAIT6 retires the half needed
// next phase; never drains to 0 mid-loop. Tail: 6 -> 0 -> none.
// ---------------------------------------------------------------------------
__global__ void __launch_bounds__(256, 2)
gemm_kernel(const float* __restrict__ v,
            const _Float16* __restrict__ wf, const _Float16* __restrict__ uf,
            const _Float16* __restrict__ bfmt,
            float* __restrict__ partials) {
  __shared__ __align__(16) _Float16 Af[3][BM * 32];  // 3 x 16 KB half-K bufs
  __shared__ __align__(16) _Float16 Bf[3][BN * 32];  // 3 x 8 KB
  __shared__ float vbuf[BM];
  __shared__ float red[2][BN];

  const int tid  = threadIdx.x;
  const int lane = tid & 63;
  const int wid  = tid >> 6;        // [0,4)
  const int wr   = wid >> 1;        // [0,2) d-half (128 rows)
  const int wc   = wid & 1;         // [0,2) s-half (64 cols)

  int bid  = blockIdx.x;
  int g    = ((bid >> 5) << 3) | (bid & 7);  // [0,512): 4 dblk siblings same XCD
  int dblk = (bid >> 3) & 3;
  int st   = g & 15;
  int b    = g >> 4;
  int s0   = st * BN;

  vbuf[tid] = v[(size_t)b * D_ + dblk * BM + tid];
  __syncthreads();  // drain v-load: every wave's vmcnt ledger starts at 0

  f32x16 acc[4][2];
#pragma unroll
  for (int i = 0; i < 4; ++i)
#pragma unroll
    for (int j = 0; j < 2; ++j)
#pragma unroll
      for (int r = 0; r < 16; ++r) acc[i][j][r] = 0.0f;

#define PH_FENCE asm volatile("" ::: "memory")
#define WAIT6 asm volatile("s_waitcnt vmcnt(6)" ::: "memory")
#define WAIT0 asm volatile("s_waitcnt vmcnt(0)" ::: "memory")

// Issue one half-K subtile: A 16KB (4 gll) + B 8KB (2 gll) = 6 vmem instr.
#define GLLH(h_, bi_) do {                                                     \
    const int kt_ = (h_) >> 1, hh_ = (h_) & 1;                                 \
    const int half_ = kt_ >> 4, ktt_ = kt_ & 15;                               \
    const _Float16* at_ = (half_ ? uf : wf)                                    \
        + (size_t)(dblk * 16 + ktt_) * 16384 + (size_t)hh_ * 8192;             \
    const _Float16* bt_ = bfmt                                                 \
        + ((size_t)(((b * 2 + half_) * 16 + ktt_) * 16 + st)) * 8192           \
        + (size_t)hh_ * 4096;                                                  \
    _Pragma("unroll")                                                          \
    for (int i = 0; i < 4; ++i)                                                \
      async_ld16(at_ + (size_t)(tid + i * 256) * 8,                            \
                 &Af[bi_][(size_t)(tid + i * 256) * 8]);                       \
    _Pragma("unroll")                                                          \
    for (int i = 0; i < 2; ++i)                                                \
      async_ld16(bt_ + (size_t)(tid + i * 256) * 8,                            \
                 &Bf[bi_][(size_t)(tid + i * 256) * 8]);                       \
  } while (0)

// Phase: 12 ds_read (this phase's frags) | issue | bar | lgkm0 | 16 MFMA |
// wait | bar | sched_barrier.  Zero-conflict reads (fragment order).
#define PHASE(bi_, ISSUE, WAITC) do {                                          \
    PH_FENCE;                                                                  \
    f16x8 a0_[4], a1_[4], b0_[2], b1_[2];                                      \
    _Pragma("unroll")                                                          \
    for (int fm = 0; fm < 4; ++fm) {                                           \
      a0_[fm] = *(const f16x8*)&Af[bi_][(size_t)((((wr * 4 + fm)) * 64 + lane)) * 8]; \
      a1_[fm] = *(const f16x8*)&Af[bi_][(size_t)(((8 + wr * 4 + fm) * 64 + lane)) * 8]; \
    }                                                                          \
    _Pragma("unroll")                                                          \
    for (int fn = 0; fn < 2; ++fn) {                                           \
      b0_[fn] = *(const f16x8*)&Bf[bi_][(size_t)((((wc * 2 + fn)) * 64 + lane)) * 8]; \
      b1_[fn] = *(const f16x8*)&Bf[bi_][(size_t)(((4 + wc * 2 + fn) * 64 + lane)) * 8]; \
    }                                                                          \
    ISSUE;                                                                     \
    __builtin_amdgcn_s_barrier();                                              \
    asm volatile("s_waitcnt lgkmcnt(0)" ::: "memory");                         \
    __builtin_amdgcn_sched_barrier(0);                                         \
    __builtin_amdgcn_s_setprio(1);                                             \
    _Pragma("unroll")                                                          \
    for (int fm = 0; fm < 4; ++fm)                                             \
      _Pragma("unroll")                                                        \
      for (int fn = 0; fn < 2; ++fn)                                           \
        acc[fm][fn] = __builtin_amdgcn_mfma_f32_32x32x16_f16(a0_[fm], b0_[fn], acc[fm][fn], 0, 0, 0); \
    _Pragma("unroll")                                                          \
    for (int fm = 0; fm < 4; ++fm)                                             \
      _Pragma("unroll")                                                        \
      for (int fn = 0; fn < 2; ++fn)                                           \
        acc[fm][fn] = __builtin_amdgcn_mfma_f32_32x32x16_f16(a1_[fm], b1_[fn], acc[fm][fn], 0, 0, 0); \
    __builtin_amdgcn_s_setprio(0);                                             \
    WAITC;                                                                     \
    __builtin_amdgcn_s_barrier();                                              \
    __builtin_amdgcn_sched_barrier(0);                                         \
  } while (0)

  // --- prologue: issue halves 0,1 (12 vmem); retire half 0 ------------------
  PH_FENCE;
  GLLH(0, 0);
  GLLH(1, 1);
  WAIT6;
  __builtin_amdgcn_s_barrier();
  __builtin_amdgcn_sched_barrier(0);

  // --- main: h = 3m,3m+1,3m+2 (m=0..19, h<=59); issue h+2, static buffers ---
  for (int m = 0; m < 20; ++m) {
    const int h = 3 * m;
    PHASE(0, GLLH(h + 2, 2), WAIT6);
    PHASE(1, GLLH(h + 3, 0), WAIT6);
    PHASE(2, GLLH(h + 4, 1), WAIT6);
  }
  // --- tail: h = 60..63; ledger drains 6 -> 0 -------------------------------
  PHASE(0, GLLH(62, 2), WAIT6);  // h=60
  PHASE(1, GLLH(63, 0), WAIT6);  // h=61
  PHASE(2, , WAIT0);             // h=62
  PHASE(0, , );                  // h=63

#undef PHASE
#undef GLLH
#undef WAIT0
#undef WAIT6
#undef PH_FENCE

  // ---- epilogue: tanh, weight by v[d], column-reduce the 256 d-rows ----
  float psum[2] = {0.f, 0.f};
#pragma unroll
  for (int fm = 0; fm < 4; ++fm)
#pragma unroll
    for (int fn = 0; fn < 2; ++fn)
#pragma unroll
      for (int r = 0; r < 16; ++r) {
        // C/D layout: col = lane&31, row = (r&3)+8*(r>>2)+4*(lane>>5)
        int row = wr * 128 + fm * 32 + (r & 3) + 8 * (r >> 2) + 4 * (lane >> 5);
        float x  = acc[fm][fn][r];
        float th = 1.0f - 2.0f / (__expf(2.0f * x) + 1.0f);  // tanh(x)
        psum[fn] += vbuf[row] * th;
      }
#pragma unroll
  for (int fn = 0; fn < 2; ++fn) psum[fn] += __shfl_xor(psum[fn], 32);
  if (lane < 32) {
    red[wr][wc * 64 + lane]      = psum[0];
    red[wr][wc * 64 + 32 + lane] = psum[1];
  }
  __syncthreads();
  if (tid < BN) {
    float val = red[0][tid] + red[1][tid];
    partials[(size_t)(dblk * B_ + b) * S_ + s0 + tid] = val;
  }
}

// ---------------------------------------------------------------------------
// gemm fallback (R10 verbatim, 256x256 tile, reg-staged B, counted vmcnt(32));
// used when ws_size can't hold the 256MB prepped-B buffer. Verified.
// ---------------------------------------------------------------------------
__global__ void __launch_bounds__(512, 2)
gemm_fb_kernel(const float* __restrict__ kten, const float* __restrict__ qten,
               const float* __restrict__ v,
               const _Float16* __restrict__ wf, const _Float16* __restrict__ uf,
               float* __restrict__ partials) {
  __shared__ __align__(16) _Float16 Af[2][256 * 64];
  __shared__ __align__(16) _Float16 Bf[2][256 * 64];
  __shared__ float vbuf[256];
  __shared__ float red[2][256];

  const int tid  = threadIdx.x;
  const int lane = tid & 63;
  const int wid  = tid >> 6;
  const int wr   = wid >> 2;
  const int wc   = wid & 3;

  int bid  = blockIdx.x;
  int g    = ((bid >> 5) << 3) | (bid & 7);
  int dblk = (bid >> 3) & 3;
  int st   = g & 7;
  int b    = g >> 3;
  int s0   = st * 256;

  if (tid < 256) vbuf[tid] = v[(size_t)b * D_ + dblk * 256 + tid];

  f32x16 acc[4][2];
#pragma unroll
  for (int i = 0; i < 4; ++i)
#pragma unroll
    for (int j = 0; j < 2; ++j)
#pragma unroll
      for (int r = 0; r < 16; ++r) acc[i][j][r] = 0.0f;

  const int nB = tid & 255;
  const int kq = tid >> 8;

#define PH_FENCE_F asm volatile("" ::: "memory")
#define PH_BAR_F __builtin_amdgcn_s_barrier()

#define GLLA_F(ktn, buf, part) do {                                            \
    const int half_ = (ktn) >> 4, ktt_ = (ktn) & 15;                           \
    const _Float16* at_ = (half_ ? uf : wf) + (size_t)(dblk * 16 + ktt_) * 16384; \
    async_ld16(at_ + (size_t)(tid + (part) * 1024) * 8,                        \
               &Af[buf][(size_t)(tid + (part) * 1024) * 8]);                   \
    async_ld16(at_ + (size_t)(tid + (part) * 1024 + 512) * 8,                  \
               &Af[buf][(size_t)(tid + (part) * 1024 + 512) * 8]);             \
  } while (0)

#define LOADB_F(ktn, xv, h) do {                                               \
    const int half_ = (ktn) >> 4, ktt_ = (ktn) & 15;                           \
    const float* col_ = (half_ ? qten : kten) + (size_t)b * (D_ * S_)          \
                        + (size_t)(ktt_ * 64) * S_ + s0 + nB                   \
                        + (size_t)(kq * 32) * S_;                              \
    _Pragma("unroll")                                                          \
    for (int j = 16 * (h); j < 16 * (h) + 16; ++j) xv[j] = col_[(size_t)j * S_]; \
  } while (0)

#define CVTWRITE_F(xv, buf) do {                                               \
    _Pragma("unroll")                                                          \
    for (int cl = 0; cl < 4; ++cl) {                                           \
      f16x8 hv_;                                                               \
      _Pragma("unroll")                                                        \
      for (int w = 0; w < 8; ++w) hv_[w] = (_Float16)xv[cl * 8 + w];           \
      int c_ = kq * 4 + cl, cks_ = c_ >> 1, clh_ = c_ & 1;                     \
      int gnl_ = ((cks_ * 8 + (nB >> 6) * 2 + ((nB >> 5) & 1)) << 6)           \
                 | (clh_ << 5) | (nB & 31);                                    \
      *(f16x8*)&Bf[buf][(size_t)gnl_ * 8] = hv_;                               \
    }                                                                          \
  } while (0)

#define COMPUTE_PHASE_F(cur_, ks_) do {                                        \
    f16x8 af_[4], bf_[2];                                                      \
    _Pragma("unroll")                                                          \
    for (int fm = 0; fm < 4; ++fm)                                             \
      af_[fm] = *(const f16x8*)&Af[cur_][(size_t)(((ks_) * 8 + wr * 4 + fm) * 64 + lane) * 8]; \
    _Pragma("unroll")                                                          \
    for (int fn = 0; fn < 2; ++fn)                                             \
      bf_[fn] = *(const f16x8*)&Bf[cur_][(size_t)(((ks_) * 8 + wc * 2 + fn) * 64 + lane) * 8]; \
    __builtin_amdgcn_s_setprio(1);                                             \
    _Pragma("unroll")                                                          \
    for (int fm = 0; fm < 4; ++fm)                                             \
      _Pragma("unroll")                                                        \
      for (int fn = 0; fn < 2; ++fn)                                           \
        acc[fm][fn] = __builtin_amdgcn_mfma_f32_32x32x16_f16(af_[fm], bf_[fn], acc[fm][fn], 0, 0, 0); \
    __builtin_amdgcn_s_setprio(0);                                             \
  } while (0)

#define STEP_F(kt_, cur_, xvC_, xvN_) do {                                     \
    const int nxt_ = (cur_) ^ 1;                                               \
    PH_FENCE_F; GLLA_F((kt_) + 1, nxt_, 0); COMPUTE_PHASE_F(cur_, 0); PH_BAR_F;\
    PH_FENCE_F; GLLA_F((kt_) + 1, nxt_, 1); COMPUTE_PHASE_F(cur_, 1); PH_BAR_F;\
    PH_FENCE_F; LOADB_F((kt_) + 2, xvN_, 0); COMPUTE_PHASE_F(cur_, 2); PH_BAR_F;\
    PH_FENCE_F; LOADB_F((kt_) + 2, xvN_, 1); CVTWRITE_F(xvC_, nxt_);           \
              COMPUTE_PHASE_F(cur_, 3);                                        \
    asm volatile("s_waitcnt vmcnt(32) lgkmcnt(0)" ::: "memory");               \
    PH_BAR_F;                                                                  \
    __builtin_amdgcn_sched_barrier(0);                                         \
  } while (0)

  float xvA[32], xvB[32];
  LOADB_F(0, xvA, 0); LOADB_F(0, xvA, 1);
  GLLA_F(0, 0, 0);    GLLA_F(0, 0, 1);
  LOADB_F(1, xvB, 0); LOADB_F(1, xvB, 1);
  CVTWRITE_F(xvA, 0);
  __syncthreads();

  for (int it = 0; it < 15; ++it) {
    STEP_F(2 * it,     0, xvB, xvA);
    STEP_F(2 * it + 1, 1, xvA, xvB);
  }

  PH_FENCE_F; GLLA_F(31, 1, 0); COMPUTE_PHASE_F(0, 0); PH_BAR_F;
  PH_FENCE_F; GLLA_F(31, 1, 1); COMPUTE_PHASE_F(0, 1); PH_BAR_F;
  PH_FENCE_F; COMPUTE_PHASE_F(0, 2); PH_BAR_F;
  PH_FENCE_F; CVTWRITE_F(xvB, 1); COMPUTE_PHASE_F(0, 3);
  __syncthreads();
  COMPUTE_PHASE_F(1, 0); COMPUTE_PHASE_F(1, 1); COMPUTE_PHASE_F(1, 2); COMPUTE_PHASE_F(1, 3);

#undef STEP_F
#undef COMPUTE_PHASE_F
#undef CVTWRITE_F
#undef LOADB_F
#undef GLLA_F
#undef PH_BAR_F
#undef PH_FENCE_F

  float psum[2] = {0.f, 0.f};
#pragma unroll
  for (int fm = 0; fm < 4; ++fm)
#pragma unroll
    for (int fn = 0; fn < 2; ++fn)
#pragma unroll
      for (int r = 0; r < 16; ++r) {
        int row = wr * 128 + fm * 32 + (r & 3) + 8 * (r >> 2) + 4 * (lane >> 5);
        float x  = acc[fm][fn][r];
        float th = 1.0f - 2.0f / (__expf(2.0f * x) + 1.0f);
        psum[fn] += vbuf[row] * th;
      }
#pragma unroll
  for (int fn = 0; fn < 2; ++fn) psum[fn] += __shfl_xor(psum[fn], 32);
  if (lane < 32) {
    red[wr][wc * 64 + lane]      = psum[0];
    red[wr][wc * 64 + 32 + lane] = psum[1];
  }
  __syncthreads();
  if (tid < 256) {
    float val = red[0][tid] + red[1][tid];
    partials[(size_t)(dblk * B_ + b) * S_ + s0 + tid] = val;
  }
}

// ---------------------------------------------------------------------------
// softmax over S per batch; sums the 4 d-block partials first. Deterministic.
// ---------------------------------------------------------------------------
__global__ void softmax_kernel(const float* __restrict__ partials, float* __restrict__ out) {
  __shared__ float logit[S_];
  __shared__ float wred[2][4];
  int b = blockIdx.x, tid = threadIdx.x;
  int lane = tid & 63, wid = tid >> 6;
  float lmax = -1e30f;
  for (int i = tid; i < S_; i += 256) {
    float acc = 0.f;
#pragma unroll
    for (int d = 0; d < 4; ++d) acc += partials[(size_t)(d * B_ + b) * S_ + i];
    logit[i] = acc;
    lmax = fmaxf(lmax, acc);
  }
#pragma unroll
  for (int o = 32; o; o >>= 1) lmax = fmaxf(lmax, __shfl_xor(lmax, o));
  if (lane == 0) wred[0][wid] = lmax;
  __syncthreads();
  float m = fmaxf(fmaxf(wred[0][0], wred[0][1]), fmaxf(wred[0][2], wred[0][3]));
  float lsum = 0.f;
  for (int i = tid; i < S_; i += 256) {
    float ex = __expf(logit[i] - m);
    logit[i] = ex;
    lsum += ex;
  }
#pragma unroll
  for (int o = 32; o; o >>= 1) lsum += __shfl_xor(lsum, o);
  if (lane == 0) wred[1][wid] = lsum;
  __syncthreads();
  float tot = wred[1][0] + wred[1][1] + wred[1][2] + wred[1][3];
  float inv = 1.0f / tot;
  for (int i = tid; i < S_; i += 256) out[(size_t)b * S_ + i] = logit[i] * inv;
}

extern "C" void kernel_launch(void* const* d_in, const int* in_sizes, int n_in,
                              void* d_out, int out_size, void* d_ws, size_t ws_size,
                              hipStream_t stream) {
  const float* q = (const float*)d_in[0];
  const float* k = (const float*)d_in[1];
  const float* v = (const float*)d_in[2];
  const float* W = (const float*)d_in[3];
  const float* U = (const float*)d_in[4];

  // ws: [wf 2MB][uf 2MB][partials 1MB][bfmt 256MB (optional)]
  _Float16* wf = (_Float16*)d_ws;
  _Float16* uf = wf + (size_t)D_ * D_;
  float* partials = (float*)(uf + (size_t)D_ * D_);
  _Float16* bfmt = (_Float16*)((char*)d_ws + 5242880);
  const size_t NEED = 5242880ull + 268435456ull;  // 262 MB

  prep_kernel<<<dim3(512, 2), 256, 0, stream>>>(W, U, wf, uf);
  if (ws_size >= NEED) {
    kqprep_kernel<<<dim3(65536), 256, 0, stream>>>(k, q, bfmt);
    gemm_kernel<<<dim3(2048), 256, 0, stream>>>(v, wf, uf, bfmt, partials);
  } else {
    gemm_fb_kernel<<<dim3(1024), 512, 0, stream>>>(k, q, v, wf, uf, partials);
  }
  softmax_kernel<<<dim3(B_), 256, 0, stream>>>(partials, (float*)d_out);
}